// Round 1
// baseline (87.296 us; speedup 1.0000x reference)
//
#include <hip/hip_runtime.h>

// Problem constants (fixed by reference setup_inputs)
#define BB 2
#define CC 8
#define HH 64
#define WW 2048
#define HALO 4          // (SEARCH-1)/2
#define TW 64
#define TH 4
#define LW (TW + 2*HALO)   // 72
#define LH (TH + 2*HALO)   // 12
#define THRESH_SCALE 0.024f  // 3 * 0.008

__global__ __launch_bounds__(TW * TH) void medror_kernel(const float* __restrict__ x,
                                                         float* __restrict__ out) {
    // Interleaved float4 per neighbor entry: (ch2, ch3, ch4, pad) -> one ds_read_b128
    __shared__ float4 lds[LH * LW];   // 12*72*16 = 13824 B

    const int b  = blockIdx.z;
    const int h0 = blockIdx.y * TH;
    const int w0 = blockIdx.x * TW;
    const int tid = threadIdx.y * TW + threadIdx.x;   // 0..255
    const int HWc = HH * WW;

    const float* xb = x + (size_t)b * CC * HWc;

    // Stage halo region of channels 2,3,4 into LDS (zero for out-of-bounds = jnp.pad)
    for (int idx = tid; idx < LH * LW; idx += TW * TH) {
        const int r = idx / LW;
        const int c = idx - r * LW;
        const int h = h0 + r - HALO;
        const int w = w0 + c - HALO;
        float4 v = make_float4(0.f, 0.f, 0.f, 0.f);
        if (h >= 0 && h < HH && w >= 0 && w < WW) {
            const int off = h * WW + w;
            v.x = xb[2 * HWc + off];
            v.y = xb[3 * HWc + off];
            v.z = xb[4 * HWc + off];
        }
        lds[idx] = v;
    }
    __syncthreads();

    const int h = h0 + threadIdx.y;
    const int w = w0 + threadIdx.x;
    const int off = h * WW + w;

    // Per-pixel thresholds and point triples for both echoes
    const float t0 = xb[0 * HWc + off] * THRESH_SCALE;
    const float t1 = xb[1 * HWc + off] * THRESH_SCALE;
    const float p0x = xb[2 * HWc + off], p0y = xb[3 * HWc + off], p0z = xb[4 * HWc + off];
    const float p1x = xb[5 * HWc + off], p1y = xb[6 * HWc + off], p1z = xb[7 * HWc + off];

    int z0 = 0, c0 = 0, z1 = 0, c1 = 0;
    const int base = threadIdx.y * LW + threadIdx.x;   // neighbor (dh=-4, dw=-4)

    for (int dh = 0; dh < 9; ++dh) {
        const int rowbase = base + dh * LW;
#pragma unroll
        for (int dw = 0; dw < 9; ++dw) {
            const float4 nb = lds[rowbase + dw];
            // echo 0
            float dx = p0x - nb.x, dy = p0y - nb.y, dz = p0z - nb.z;
            float d2 = dx * dx + dy * dy + dz * dz;
            if (d2 == 0.0f)            z0++;
            else if (sqrtf(d2) <= t0)  c0++;
            // echo 1 (same neighbor, different point triple)
            dx = p1x - nb.x; dy = p1y - nb.y; dz = p1z - nb.z;
            d2 = dx * dx + dy * dy + dz * dz;
            if (d2 == 0.0f)            z1++;
            else if (sqrtf(d2) <= t1)  c1++;
        }
    }

    // top-9-smallest qualifying count = min(c, max(9 - z, 0))
    const int avail0 = 9 - z0;
    const int avail1 = 9 - z1;
    const int k0 = min(c0, avail0 > 0 ? avail0 : 0);
    const int k1 = min(c1, avail1 > 0 ? avail1 : 0);

    out[((size_t)b * 2 + 0) * HWc + off] = (k0 < 3) ? 1000.0f : -1000.0f;
    out[((size_t)b * 2 + 1) * HWc + off] = (k1 < 3) ? 1000.0f : -1000.0f;
}

extern "C" void kernel_launch(void* const* d_in, const int* in_sizes, int n_in,
                              void* d_out, int out_size, void* d_ws, size_t ws_size,
                              hipStream_t stream) {
    const float* x = (const float*)d_in[0];
    float* out = (float*)d_out;
    dim3 grid(WW / TW, HH / TH, BB);   // 32 x 16 x 2 = 1024 blocks
    dim3 block(TW, TH);                // 256 threads
    medror_kernel<<<grid, block, 0, stream>>>(x, out);
}

// Round 2
// 68.284 us; speedup vs baseline: 1.2784x; 1.2784x over previous
//
#include <hip/hip_runtime.h>

// Problem constants (fixed by reference setup_inputs)
#define BB 2
#define CC 8
#define HH 64
#define WW 2048
#define HALO 4          // (SEARCH-1)/2
#define TW 64
#define TH 4
#define LW (TW + 2*HALO)   // 72
#define LH (TH + 2*HALO)   // 12
#define THRESH_SCALE 0.024f  // 3 * 0.008

typedef float vf2 __attribute__((ext_vector_type(2)));
typedef int   vi2 __attribute__((ext_vector_type(2)));

__global__ __launch_bounds__(TW * TH) void medror_kernel(const float* __restrict__ x,
                                                         float* __restrict__ out) {
    // Interleaved float4 per neighbor entry: (ch2, ch3, ch4, pad) -> one ds_read_b128
    __shared__ float4 lds[LH * LW];   // 12*72*16 = 13824 B

    const int b  = blockIdx.z;
    const int h0 = blockIdx.y * TH;
    const int w0 = blockIdx.x * TW;
    const int tid = threadIdx.y * TW + threadIdx.x;   // 0..255
    const int HWc = HH * WW;

    const float* xb = x + (size_t)b * CC * HWc;

    // Stage halo region of channels 2,3,4 into LDS (zero for out-of-bounds = jnp.pad)
    for (int idx = tid; idx < LH * LW; idx += TW * TH) {
        const int r = idx / LW;
        const int c = idx - r * LW;
        const int h = h0 + r - HALO;
        const int w = w0 + c - HALO;
        float4 v = make_float4(0.f, 0.f, 0.f, 0.f);
        if (h >= 0 && h < HH && w >= 0 && w < WW) {
            const int off = h * WW + w;
            v.x = xb[2 * HWc + off];
            v.y = xb[3 * HWc + off];
            v.z = xb[4 * HWc + off];
        }
        lds[idx] = v;
    }
    __syncthreads();

    const int h = h0 + threadIdx.y;
    const int w = w0 + threadIdx.x;
    const int off = h * WW + w;

    // Pack the two echoes into lane-local 2-vectors -> v_pk_* dual-fp32 ops
    const float t0 = xb[0 * HWc + off] * THRESH_SCALE;
    const float t1 = xb[1 * HWc + off] * THRESH_SCALE;
    vf2 t2; t2.x = t0 * t0; t2.y = t1 * t1;   // sqrt(d2)<=t  <=>  d2<=t^2  (t>=0)
    vf2 px; px.x = xb[2 * HWc + off]; px.y = xb[5 * HWc + off];
    vf2 py; py.x = xb[3 * HWc + off]; py.y = xb[6 * HWc + off];
    vf2 pz; pz.x = xb[4 * HWc + off]; pz.y = xb[7 * HWc + off];

    vi2 le = {0, 0};   // count(d2 <= t^2)  (includes exact zeros)
    vi2 zz = {0, 0};   // count(d2 == 0)
    const int base = threadIdx.y * LW + threadIdx.x;   // neighbor (dh=-4, dw=-4)

    for (int dh = 0; dh < 9; ++dh) {
        const int rowbase = base + dh * LW;
#pragma unroll
        for (int dw = 0; dw < 9; ++dw) {
            const float4 nb = lds[rowbase + dw];
            vf2 dx = px - nb.x;
            vf2 dy = py - nb.y;
            vf2 dz = pz - nb.z;
            vf2 d2 = dx * dx + dy * dy + dz * dz;
            le -= (d2 <= t2);          // vector cmp yields 0 / -1 per component
            le += (d2 == 0.0f);        // exclude exact zeros from "qualifying"
            zz -= (d2 == 0.0f);
        }
    }

    // top-9-smallest qualifying count = min(c, max(9 - z, 0)); output ±1000
    const int avail0 = 9 - zz.x;
    const int avail1 = 9 - zz.y;
    const int k0 = min(le.x, avail0 > 0 ? avail0 : 0);
    const int k1 = min(le.y, avail1 > 0 ? avail1 : 0);

    out[((size_t)b * 2 + 0) * HWc + off] = (k0 < 3) ? 1000.0f : -1000.0f;
    out[((size_t)b * 2 + 1) * HWc + off] = (k1 < 3) ? 1000.0f : -1000.0f;
}

extern "C" void kernel_launch(void* const* d_in, const int* in_sizes, int n_in,
                              void* d_out, int out_size, void* d_ws, size_t ws_size,
                              hipStream_t stream) {
    const float* x = (const float*)d_in[0];
    float* out = (float*)d_out;
    dim3 grid(WW / TW, HH / TH, BB);   // 32 x 16 x 2 = 1024 blocks
    dim3 block(TW, TH);                // 256 threads
    medror_kernel<<<grid, block, 0, stream>>>(x, out);
}